// Round 12
// baseline (583.826 us; speedup 1.0000x reference)
//
#include <hip/hip_runtime.h>
#include <cstdint>
#include <cstddef>

// Problem constants
#define Bc 16
#define Lc 1024
#define DMc 512
#define Hc 8
#define DHc 2048
#define Uc 35        // FACTOR*ceil(ln(L)) = 5*7, fixed by problem setup

#define FILL_BLKS 16384                              // per GEMM launch (half of 32768)
#define PREP_BLKS (8192 + 4 * 256 + 2 * 1024 + 1 + 128)   // +128 rowsel-zero blocks

typedef __attribute__((ext_vector_type(8))) short bf16x8;
typedef __attribute__((ext_vector_type(4))) float f32x4;

__device__ __forceinline__ ushort f2bf(float f) {
    union { float f; uint32_t u; } v; v.f = f;
    uint32_t r = v.u + 0x7FFF + ((v.u >> 16) & 1);   // round-to-nearest-even
    return (ushort)(r >> 16);
}
__device__ __forceinline__ float bf2f(ushort u) {
    union { uint32_t i; float f; } v; v.i = ((uint32_t)u) << 16; return v.f;
}

// async global->LDS, 16 bytes per lane; LDS dest must be wave-uniform base
__device__ __forceinline__ void glds16(const ushort* g, ushort* l) {
    __builtin_amdgcn_global_load_lds(
        (__attribute__((address_space(1))) void*)(void*)const_cast<ushort*>(g),
        (__attribute__((address_space(3))) void*)l, 16, 0, 0);
}

// ---------------------------------------------------------------------------
// bf16 MFMA GEMM: C[M,N] = A[M,K] @ Bt[N,K]^T + bias.
// 128x128 tile, BK=32, TRIPLE-buffered LDS with depth-2 prefetch and counted
// vmcnt (loads stay in flight across the barrier — T3/T4 recipe):
//   iter t: issue stage(t+2); compute tile t; s_waitcnt vmcnt(4); s_barrier.
//   Each stage = exactly 4 global_load_lds per thread, so vmcnt(4) means
//   "tile t+1's loads have landed" (t+2's 4 may remain in flight).
// Blocks [0, nblk): GEMM (XCD-swizzled within nblk; nblk % 8 == 0).
// If FILL: blocks [nblk, nblk+FILL_BLKS) write 1/L into score rows whose
// rowsel flag is 0 (selected rows already hold final probs), non-temporal.
// MODE: 0 = f32 out; 1 = bf16 out; 2 = relu + bf16 out
// ---------------------------------------------------------------------------
template<int MODE, int FILL>
__global__ __launch_bounds__(256) void gemm_mfma(
    const ushort* __restrict__ A, const ushort* __restrict__ Bt,
    const float* __restrict__ bias, void* __restrict__ out0,
    int M, int N, int K, int nxb, int nblk,
    float* __restrict__ fillbuf, const int* __restrict__ rowsel, int fill_base)
{
    const int tid = threadIdx.x;
    if (FILL && (int)blockIdx.x >= nblk) {
        int fb = (blockIdx.x - nblk) + fill_base;    // group of 4 score rows
        const float iv = 1.0f / (float)Lc;
        f32x4 v4 = {iv, iv, iv, iv};
        #pragma unroll
        for (int r = 0; r < 4; ++r) {
            int row = fb * 4 + r;
            if (rowsel[row] == 0)
                __builtin_nontemporal_store(
                    v4, reinterpret_cast<f32x4*>(fillbuf + (size_t)row * Lc) + tid);
        }
        return;
    }

    __shared__ ushort As[3][128 * 32];
    __shared__ ushort Bs[3][128 * 32];
    int wg = blockIdx.x;
    wg = (wg & 7) * (nblk >> 3) + (wg >> 3);     // XCD swizzle (nblk%8==0)
    const int n0 = (wg % nxb) * 128;
    const int m0 = (wg / nxb) * 128;

    const int lane = tid & 63;
    const int wave = tid >> 6;
    const int wr = wave >> 1, wc = wave & 1;
    const int lrow = lane & 15;
    const int lk = (lane >> 4) * 8;

    f32x4 zero = {0.f, 0.f, 0.f, 0.f};
    f32x4 acc[4][4];
    #pragma unroll
    for (int m = 0; m < 4; ++m)
        #pragma unroll
        for (int n = 0; n < 4; ++n) acc[m][n] = zero;

    const int srow = tid >> 2;            // 0..63
    const int skc = (tid & 3) * 8;        // 0,8,16,24
    const int ldsb = (tid & 192) * 8;     // wave * 512 elements

    auto stage = [&](int k0, int bufi) {  // exactly 4 glds16 per thread
        glds16(A  + (size_t)(m0 + srow) * K + k0 + skc,      &As[bufi][ldsb]);
        glds16(A  + (size_t)(m0 + 64 + srow) * K + k0 + skc, &As[bufi][2048 + ldsb]);
        glds16(Bt + (size_t)(n0 + srow) * K + k0 + skc,      &Bs[bufi][ldsb]);
        glds16(Bt + (size_t)(n0 + 64 + srow) * K + k0 + skc, &Bs[bufi][2048 + ldsb]);
    };

    const int nt = K >> 5;                // >= 16 for all shapes here

    // prologue: tiles 0,1 in flight; wait for tile 0 only
    stage(0, 0);
    stage(32, 1);
    asm volatile("s_waitcnt vmcnt(4)" ::: "memory");
    __builtin_amdgcn_sched_barrier(0);
    __builtin_amdgcn_s_barrier();
    __builtin_amdgcn_sched_barrier(0);

    int bcur = 0;
    for (int t = 0; t < nt; ++t) {
        int bpre = bcur + 2; if (bpre >= 3) bpre -= 3;
        if (t + 2 < nt) stage((t + 2) << 5, bpre);   // depth-2 prefetch

        bf16x8 af[4], bv[4];
        #pragma unroll
        for (int m = 0; m < 4; ++m)
            af[m] = *reinterpret_cast<const bf16x8*>(&As[bcur][(wr * 64 + m * 16 + lrow) * 32 + lk]);
        #pragma unroll
        for (int n = 0; n < 4; ++n)
            bv[n] = *reinterpret_cast<const bf16x8*>(&Bs[bcur][(wc * 64 + n * 16 + lrow) * 32 + lk]);
        #pragma unroll
        for (int m = 0; m < 4; ++m)
            #pragma unroll
            for (int n = 0; n < 4; ++n)
                acc[m][n] = __builtin_amdgcn_mfma_f32_16x16x32_bf16(af[m], bv[n], acc[m][n], 0, 0, 0);

        if (t + 1 < nt) {
            // tile t's ds_reads drained by compiler lgkmcnt before last MFMA;
            // wait for tile t+1's loads (leave t+2's 4 in flight), then sync.
            if (t + 2 < nt) asm volatile("s_waitcnt vmcnt(4)" ::: "memory");
            else            asm volatile("s_waitcnt vmcnt(0)" ::: "memory");
            __builtin_amdgcn_sched_barrier(0);
            __builtin_amdgcn_s_barrier();
            __builtin_amdgcn_sched_barrier(0);
        }
        bcur = (bcur + 1 == 3) ? 0 : bcur + 1;
    }

    #pragma unroll
    for (int n = 0; n < 4; ++n) {
        int col = n0 + wc * 64 + n * 16 + lrow;
        float bval = bias[col];
        #pragma unroll
        for (int m = 0; m < 4; ++m) {
            #pragma unroll
            for (int j = 0; j < 4; ++j) {
                int row = m0 + wr * 64 + m * 16 + (lane >> 4) * 4 + j;
                float v = acc[m][n][j] + bval;
                if (MODE == 2) v = fmaxf(v, 0.0f);
                if (MODE == 0)
                    ((float*)out0)[(size_t)row * N + col] = v;
                else
                    ((ushort*)out0)[(size_t)row * N + col] = f2bf(v);
            }
        }
    }
}

// ---------------------------------------------------------------------------
// Fused prep: x->bf16, weight transposes to [N][K] bf16, bias concat,
// rowsel zeroing (must precede topk).
// ---------------------------------------------------------------------------
__device__ __forceinline__ void tr_tile(
    const float* __restrict__ in, ushort* __restrict__ out,
    int K, int N, int bx, int by, float (*t)[33], int tid)
{
    int n0 = bx * 32, k0 = by * 32;
    int tx = tid & 31, ty = tid >> 5;
    #pragma unroll
    for (int dy = 0; dy < 32; dy += 8)
        t[ty + dy][tx] = in[(size_t)(k0 + ty + dy) * N + n0 + tx];
    __syncthreads();
    #pragma unroll
    for (int dy = 0; dy < 32; dy += 8)
        out[(size_t)(n0 + ty + dy) * K + k0 + tx] = f2bf(t[tx][ty + dy]);
}

__global__ __launch_bounds__(256) void prep_kernel(
    const float* __restrict__ x,
    const float* __restrict__ Wq, const float* __restrict__ Wk,
    const float* __restrict__ Wv, const float* __restrict__ Wo,
    const float* __restrict__ W1, const float* __restrict__ W2,
    const float* __restrict__ bq, const float* __restrict__ bk,
    const float* __restrict__ bv,
    ushort* __restrict__ xbf, ushort* __restrict__ Wqkvt,
    ushort* __restrict__ Wot, ushort* __restrict__ W1t,
    ushort* __restrict__ W2t, float* __restrict__ bcat,
    int* __restrict__ rowsel)
{
    __shared__ float t[32][33];
    const int tid = threadIdx.x;
    int bid = blockIdx.x;
    if (bid < 8192) {   // x -> bf16 (float4 per thread)
        int i = bid * 256 + tid;
        float4 v = reinterpret_cast<const float4*>(x)[i];
        uint32_t lo = (uint32_t)f2bf(v.x) | ((uint32_t)f2bf(v.y) << 16);
        uint32_t hi = (uint32_t)f2bf(v.z) | ((uint32_t)f2bf(v.w) << 16);
        reinterpret_cast<uint2*>(xbf)[i] = make_uint2(lo, hi);
        return;
    }
    bid -= 8192;
    if (bid < 256) { tr_tile(Wq, Wqkvt,              512, 512, bid & 15, bid >> 4, t, tid); return; }
    bid -= 256;
    if (bid < 256) { tr_tile(Wk, Wqkvt + 512 * 512,  512, 512, bid & 15, bid >> 4, t, tid); return; }
    bid -= 256;
    if (bid < 256) { tr_tile(Wv, Wqkvt + 1024 * 512, 512, 512, bid & 15, bid >> 4, t, tid); return; }
    bid -= 256;
    if (bid < 256) { tr_tile(Wo, Wot,                512, 512, bid & 15, bid >> 4, t, tid); return; }
    bid -= 256;
    if (bid < 1024) { tr_tile(W1, W1t,               512, 2048, bid & 63, bid >> 6, t, tid); return; }
    bid -= 1024;
    if (bid < 1024) { tr_tile(W2, W2t,               2048, 512, bid & 15, bid >> 4, t, tid); return; }
    bid -= 1024;
    if (bid < 1) {
        for (int i = tid; i < 1536; i += 256)
            bcat[i] = (i < 512) ? bq[i] : (i < 1024) ? bk[i - 512] : bv[i - 1024];
        return;
    }
    bid -= 1;
    // zero rowsel: 131072 ints = 32768 uint4 over 128 blocks
    reinterpret_cast<uint4*>(rowsel)[bid * 256 + tid] = make_uint4(0, 0, 0, 0);
}

// ---------------------------------------------------------------------------
// compute_M: lane = sample. Wave per (b,h,l).
// QKV layout: [b*L+l][Q(512) | K(512) | V(512)] bf16, row stride 1536.
// ---------------------------------------------------------------------------
__global__ __launch_bounds__(256) void compute_M_kernel(
    const ushort* __restrict__ QKV, const int* __restrict__ idx,
    float* __restrict__ Mout)
{
    __shared__ float qs[4][64];
    const int tid = threadIdx.x;
    const int wid = tid >> 6;
    const int lane = tid & 63;
    const int task = blockIdx.x * 4 + wid;     // (b,h,l)
    const int l = task & (Lc - 1);
    const int bh = task >> 10;
    const int h = bh & (Hc - 1);
    const int b = bh >> 3;

    qs[wid][lane] = bf2f(QKV[(size_t)(b * Lc + l) * 1536 + h * 64 + lane]);

    const bool act = lane < Uc;
    int kl = act ? idx[l * Uc + lane] : 0;
    const bf16x8* kr = reinterpret_cast<const bf16x8*>(
        QKV + (size_t)(b * Lc + kl) * 1536 + 512 + h * 64);
    float dot = 0.0f;
    if (act) {
        #pragma unroll
        for (int c = 0; c < 8; ++c) {
            bf16x8 kv = kr[c];
            #pragma unroll
            for (int e = 0; e < 8; ++e)
                dot += qs[wid][c * 8 + e] * bf2f((ushort)kv[e]);
        }
    }
    float mx = act ? dot : -INFINITY;
    float sm = act ? dot : 0.0f;
    #pragma unroll
    for (int off = 32; off; off >>= 1) {
        mx = fmaxf(mx, __shfl_xor(mx, off, 64));
        sm += __shfl_xor(sm, off, 64);
    }
    if (lane == 0) Mout[task] = mx - sm * (1.0f / Uc);
}

// ---------------------------------------------------------------------------
// Top-u per (b,h): register-resident values, wave shfl reduce.
// Tie-break lowest index (matches lax.top_k selected set).
// Also sets rowsel[bh*1024 + idx] = 1 for selected rows.
// ---------------------------------------------------------------------------
__global__ __launch_bounds__(256) void topk_kernel(
    const float* __restrict__ Mvals, int* __restrict__ Mtop,
    int* __restrict__ rowsel)
{
    const int bh = blockIdx.x;
    const int t = threadIdx.x;
    const int lane = t & 63, wid = t >> 6;
    float v[4];
    #pragma unroll
    for (int c = 0; c < 4; ++c) v[c] = Mvals[((size_t)bh << 10) + t + 256 * c];

    __shared__ float cv[4];
    __shared__ int   ci[4];
    __shared__ int   wini;

    for (int j = 0; j < Uc; ++j) {
        float bv = v[0]; int bi = t;
        #pragma unroll
        for (int c = 1; c < 4; ++c)
            if (v[c] > bv) { bv = v[c]; bi = t + 256 * c; }   // strict > keeps lower idx
        #pragma unroll
        for (int off = 32; off; off >>= 1) {
            float ov = __shfl_xor(bv, off, 64);
            int   oi = __shfl_xor(bi, off, 64);
            if (ov > bv || (ov == bv && oi < bi)) { bv = ov; bi = oi; }
        }
        if (lane == 0) { cv[wid] = bv; ci[wid] = bi; }
        __syncthreads();
        if (t == 0) {
            float fv = cv[0]; int fi = ci[0];
            #pragma unroll
            for (int w = 1; w < 4; ++w)
                if (cv[w] > fv || (cv[w] == fv && ci[w] < fi)) { fv = cv[w]; fi = ci[w]; }
            Mtop[bh * Uc + j] = fi;
            rowsel[(bh << 10) + fi] = 1;
            wini = fi;
        }
        __syncthreads();
        int wi = wini;
        if ((wi & 255) == t) v[wi >> 8] = -INFINITY;
    }
}

// ---------------------------------------------------------------------------
// QK scores: block per (b,h, l-chunk of 256). Thread owns one K row (bf16,
// read once); Q_reduce rows broadcast from LDS. Writes RAW S into the
// selected rows of score_out.
// ---------------------------------------------------------------------------
__global__ __launch_bounds__(256) void qk_scores_kernel(
    const ushort* __restrict__ QKV, const int* __restrict__ Mtop,
    float* __restrict__ score)
{
    const int bh = blockIdx.x >> 2;
    const int l0 = (blockIdx.x & 3) * 256;
    const int h = bh & (Hc - 1), b = bh >> 3;
    __shared__ int qpos[Uc];
    __shared__ float Qs[Uc][64];
    const int t = threadIdx.x;
    if (t < Uc) qpos[t] = Mtop[bh * Uc + t];
    __syncthreads();
    for (int i = t; i < Uc * 64; i += 256) {
        int j = i >> 6, d = i & 63;
        Qs[j][d] = bf2f(QKV[(size_t)(b * Lc + qpos[j]) * 1536 + h * 64 + d]);
    }
    __syncthreads();

    const int l = l0 + t;
    const bf16x8* kr = reinterpret_cast<const bf16x8*>(
        QKV + (size_t)(b * Lc + l) * 1536 + 512 + h * 64);
    float acc[Uc] = {};
    #pragma unroll
    for (int c = 0; c < 8; ++c) {
        bf16x8 kv = kr[c];
        float kf[8];
        #pragma unroll
        for (int e = 0; e < 8; ++e) kf[e] = bf2f((ushort)kv[e]);
        #pragma unroll
        for (int j = 0; j < Uc; ++j) {
            float s = 0.0f;
            #pragma unroll
            for (int e = 0; e < 8; ++e) s += Qs[j][c * 8 + e] * kf[e];
            acc[j] += s;
        }
    }
    #pragma unroll
    for (int j = 0; j < Uc; ++j)
        score[((size_t)(bh << 10) + qpos[j]) * Lc + l] = acc[j] * 0.125f;
}

// ---------------------------------------------------------------------------
// Fused attention output: block per (b,h), 256 threads (64 d x 4 part).
// Phase A: softmax stats of 35 raw rows (in score_out).
// Phase B: probs -> LDS + score_out; single V sweep (bf16) for PV + V-mean.
// Phase C: ctx = mean rows everywhere, PV on selected rows.
// ---------------------------------------------------------------------------
__global__ __launch_bounds__(256) void attn_out_kernel(
    float* __restrict__ score, const ushort* __restrict__ QKV,
    const int* __restrict__ Mtop, ushort* __restrict__ ctx)
{
    const int bh = blockIdx.x;
    const int h = bh & (Hc - 1), b = bh >> 3;
    const int t = threadIdx.x;
    const int d = t & 63, part = t >> 6;

    __shared__ int qpos[Uc];
    __shared__ float mz[Uc][2];
    __shared__ float buf[4][Uc][64];   // prob chunk staging, then PV partials
    __shared__ float vmred[4][64];
    __shared__ float vmf[64];

    if (t < Uc) qpos[t] = Mtop[bh * Uc + t];
    __syncthreads();

    // Phase A: m_j, 1/Z_j (raw rows untouched)
    for (int j = part; j < Uc; j += 4) {
        const float* row = score + ((size_t)(bh << 10) + qpos[j]) * Lc;
        float v[16];
        float mx = -INFINITY;
        #pragma unroll
        for (int c = 0; c < 16; ++c) { v[c] = row[c * 64 + d]; mx = fmaxf(mx, v[c]); }
        #pragma unroll
        for (int off = 32; off; off >>= 1) mx = fmaxf(mx, __shfl_xor(mx, off, 64));
        float z = 0.0f;
        #pragma unroll
        for (int c = 0; c < 16; ++c) z += expf(v[c] - mx);
        #pragma unroll
        for (int off = 32; off; off >>= 1) z += __shfl_xor(z, off, 64);
        if (d == 0) { mz[j][0] = mx; mz[j][1] = 1.0f / z; }
    }
    __syncthreads();

    // Phase B: V sweep (bf16) with on-the-fly probs
    float acc[Uc];
    #pragma unroll
    for (int j = 0; j < Uc; ++j) acc[j] = 0.0f;
    float vm = 0.0f;

    for (int c = 0; c < 4; ++c) {
        const int l0 = part * 256 + c * 64;
        #pragma unroll
        for (int j = 0; j < Uc; ++j) {
            size_t off = ((size_t)(bh << 10) + qpos[j]) * Lc + l0 + d;
            float p = expf(score[off] - mz[j][0]) * mz[j][1];
            buf[part][j][d] = p;
            score[off] = p;                 // final prob (never re-read here)
        }
        __syncthreads();
        #pragma unroll 4
        for (int li = 0; li < 64; ++li) {
            float v = bf2f(QKV[((size_t)(b << 10) + l0 + li) * 1536 + 1024 + h * 64 + d]);
            vm += v;
            #pragma unroll
            for (int j = 0; j < Uc; ++j) acc[j] += buf[part][j][li] * v;
        }
        __syncthreads();
    }

    // PV partials + mean partials into LDS
    #pragma unroll
    for (int j = 0; j < Uc; ++j) buf[part][j][d] = acc[j];
    vmred[part][d] = vm;
    __syncthreads();
    if (t < 64) vmf[t] = (vmred[0][t] + vmred[1][t] + vmred[2][t] + vmred[3][t]) * (1.0f / Lc);
    __syncthreads();

    // Phase C1: default (mean) rows for ALL l
    const int dcol = (t & 15) * 4;
    ushort4 vmu;
    vmu.x = f2bf(vmf[dcol + 0]); vmu.y = f2bf(vmf[dcol + 1]);
    vmu.z = f2bf(vmf[dcol + 2]); vmu.w = f2bf(vmf[dcol + 3]);
    for (int li = 0; li < 64; ++li) {
        int l = (t >> 4) + li * 16;
        *reinterpret_cast<ushort4*>(ctx + ((size_t)(b << 10) + l) * 512 + h * 64 + dcol) = vmu;
    }
    __syncthreads();   // drain default writes before overwriting selected rows

    // Phase C2: selected rows = PV
    for (int idx = t; idx < Uc * 64; idx += 256) {
        int j = idx >> 6, d2 = idx & 63;
        float s = buf[0][j][d2] + buf[1][j][d2] + buf[2][j][d2] + buf[3][j][d2];
        ctx[((size_t)(b << 10) + qpos[j]) * 512 + h * 64 + d2] = f2bf(s);
    }
}

// ---------------------------------------------------------------------------
// LayerNorm(a + b) * g + beta over DM=512. Thread handles elems 2t, 2t+1.
// ---------------------------------------------------------------------------
template<int A_BF, int B_BF, int OUT_BF>
__global__ __launch_bounds__(256) void ln_kernel(
    const void* __restrict__ a, const void* __restrict__ bsrc,
    const float* __restrict__ g, const float* __restrict__ beta,
    void* __restrict__ y)
{
    const int row = blockIdx.x;
    const int t = threadIdx.x;
    float a0, a1, b0, b1;
    if (A_BF) {
        uint32_t u = ((const uint32_t*)a)[(size_t)row * 256 + t];
        a0 = bf2f((ushort)(u & 0xffff)); a1 = bf2f((ushort)(u >> 16));
    } else {
        float2 f = ((const float2*)a)[(size_t)row * 256 + t];
        a0 = f.x; a1 = f.y;
    }
    if (B_BF) {
        uint32_t u = ((const uint32_t*)bsrc)[(size_t)row * 256 + t];
        b0 = bf2f((ushort)(u & 0xffff)); b1 = bf2f((ushort)(u >> 16));
    } else {
        float2 f = ((const float2*)bsrc)[(size_t)row * 256 + t];
        b0 = f.x; b1 = f.y;
    }
    float v0 = a0 + b0, v1 = a1 + b1;
    __shared__ float red[256];
    red[t] = v0 + v1; __syncthreads();
    for (int s = 128; s; s >>= 1) { if (t < s) red[t] += red[t + s]; __syncthreads(); }
    float mean = red[0] * (1.0f / DMc);
    __syncthreads();
    float d0 = v0 - mean, d1 = v1 - mean;
    red[t] = d0 * d0 + d1 * d1; __syncthreads();
    for (int s = 128; s; s >>= 1) { if (t < s) red[t] += red[t + s]; __syncthreads(); }
    float inv = rsqrtf(red[0] * (1.0f / DMc) + 1e-5f);
    float2 gv = ((const float2*)g)[t];
    float2 bt = ((const float2*)beta)[t];
    float o0 = gv.x * d0 * inv + bt.x;
    float o1 = gv.y * d1 * inv + bt.y;
    if (OUT_BF) {
        uint32_t u = (uint32_t)f2bf(o0) | ((uint32_t)f2bf(o1) << 16);
        ((uint32_t*)y)[(size_t)row * 256 + t] = u;
    } else {
        ((float2*)y)[(size_t)row * 256 + t] = make_float2(o0, o1);
    }
}

// ---------------------------------------------------------------------------
extern "C" void kernel_launch(void* const* d_in, const int* in_sizes, int n_in,
                              void* d_out, int out_size, void* d_ws, size_t ws_size,
                              hipStream_t stream)
{
    const float* x     = (const float*)d_in[0];
    const float* Wq    = (const float*)d_in[1];
    const float* bq    = (const float*)d_in[2];
    const float* Wk    = (const float*)d_in[3];
    const float* bk    = (const float*)d_in[4];
    const float* Wv    = (const float*)d_in[5];
    const float* bv    = (const float*)d_in[6];
    const float* Wo    = (const float*)d_in[7];
    const float* bo    = (const float*)d_in[8];
    const float* g1    = (const float*)d_in[9];
    const float* beta1 = (const float*)d_in[10];
    const float* W1    = (const float*)d_in[11];
    const float* bf1   = (const float*)d_in[12];
    const float* W2    = (const float*)d_in[13];
    const float* bf2   = (const float*)d_in[14];
    const float* g2    = (const float*)d_in[15];
    const float* beta2 = (const float*)d_in[16];
    const int* index_sample = (const int*)d_in[17];

    const size_t NTOK = (size_t)Bc * Lc;            // 16384
    const size_t QKV_SZ = NTOK * DMc;               // 8,388,608
    const size_t HID_SZ = NTOK * DHc;

    char* p = (char*)d_ws;
    auto alloc = [&](size_t bytes) { char* r = p; p += (bytes + 255) & ~(size_t)255; return r; };
    ushort* QKVbf  = (ushort*)alloc(NTOK * 1536 * 2);   // [tok][Q|K|V] bf16
    ushort* hidden = (ushort*)alloc(HID_SZ * 2);
    ushort* xbf    = (ushort*)alloc(QKV_SZ * 2);
    ushort* ctxbf  = (ushort*)alloc(QKV_SZ * 2);
    ushort* x1bf   = (ushort*)alloc(QKV_SZ * 2);
    ushort* projbf = (ushort*)alloc(QKV_SZ * 2);
    ushort* ffnbf  = (ushort*)alloc(QKV_SZ * 2);
    ushort* Wqkvt  = (ushort*)alloc((size_t)1536 * 512 * 2);
    ushort* Wot    = (ushort*)alloc((size_t)512 * 512 * 2);
    ushort* W1t    = (ushort*)alloc((size_t)512 * 2048 * 2);
    ushort* W2t    = (ushort*)alloc((size_t)512 * 2048 * 2);
    float*  bcat   = (float*) alloc(1536 * 4);
    float*  Mbuf   = (float*) alloc((size_t)Bc * Hc * Lc * 4);
    int*    Mtop   = (int*)   alloc((size_t)Bc * Hc * 64 * 4);
    int*    rowsel = (int*)   alloc((size_t)Bc * Hc * Lc * 4);   // 512KB flags

    float* x2_out    = (float*)d_out;
    float* score_out = x2_out + QKV_SZ;

    dim3 blk(256);

    // prep: x->bf16, weight transposes, bias concat, rowsel zero
    prep_kernel<<<PREP_BLKS, blk, 0, stream>>>(
        x, Wq, Wk, Wv, Wo, W1, W2, bq, bk, bv,
        xbf, Wqkvt, Wot, W1t, W2t, bcat, rowsel);

    // fused QKV projection -> [tok][Q|K|V] bf16
    gemm_mfma<1, 0><<<12 * 128, blk, 0, stream>>>(
        xbf, Wqkvt, bcat, QKVbf, (int)NTOK, 1536, 512, 12, 12 * 128,
        nullptr, nullptr, 0);

    // ProbSparse selection (topk also sets rowsel flags)
    compute_M_kernel<<<(Bc * Hc * Lc) / 4, blk, 0, stream>>>(QKVbf, index_sample, Mbuf);
    topk_kernel<<<Bc * Hc, blk, 0, stream>>>(Mbuf, Mtop, rowsel);

    // raw scores into selected score rows, then softmax+PV+ctx
    qk_scores_kernel<<<Bc * Hc * 4, blk, 0, stream>>>(QKVbf, Mtop, score_out);
    attn_out_kernel<<<Bc * Hc, blk, 0, stream>>>(score_out, QKVbf, Mtop, ctxbf);

    // output projection (bf16) + LN1 -> x1 (bf16); residual from xbf
    gemm_mfma<1, 0><<<4 * 128, blk, 0, stream>>>(
        ctxbf, Wot, bo, projbf, (int)NTOK, 512, 512, 4, 4 * 128,
        nullptr, nullptr, 0);
    ln_kernel<1, 1, 1><<<(int)NTOK, blk, 0, stream>>>(projbf, xbf, g1, beta1, x1bf);

    // FFN1 + first half of score default fill (hidden under MFMA)
    gemm_mfma<2, 1><<<16 * 128 + FILL_BLKS, blk, 0, stream>>>(
        x1bf, W1t, bf1, hidden, (int)NTOK, 2048, 512, 16, 16 * 128,
        score_out, rowsel, 0);
    // FFN2 + second half of fill
    gemm_mfma<1, 1><<<4 * 128 + FILL_BLKS, blk, 0, stream>>>(
        hidden, W2t, bf2, ffnbf, (int)NTOK, 512, 2048, 4, 4 * 128,
        score_out, rowsel, FILL_BLKS);
    ln_kernel<1, 1, 0><<<(int)NTOK, blk, 0, stream>>>(ffnbf, x1bf, g2, beta2, x2_out);
}

// Round 13
// 572.857 us; speedup vs baseline: 1.0191x; 1.0191x over previous
//
#include <hip/hip_runtime.h>
#include <cstdint>
#include <cstddef>

// Problem constants
#define Bc 16
#define Lc 1024
#define DMc 512
#define Hc 8
#define DHc 2048
#define Uc 35        // FACTOR*ceil(ln(L)) = 5*7, fixed by problem setup

#define FILL_BLKS 16384                  // per FFN GEMM launch (half of 32768)
#define AUX_BLKS (256 + 1024 + 1024 + 128)   // Wo/W1/W2 transposes + rowsel zero
#define PREP_BLKS (8192 + 3 * 256 + 1)       // x-conv + Wq/Wk/Wv transposes + bias

typedef __attribute__((ext_vector_type(8))) short bf16x8;
typedef __attribute__((ext_vector_type(4))) float f32x4;

__device__ __forceinline__ ushort f2bf(float f) {
    union { float f; uint32_t u; } v; v.f = f;
    uint32_t r = v.u + 0x7FFF + ((v.u >> 16) & 1);   // round-to-nearest-even
    return (ushort)(r >> 16);
}
__device__ __forceinline__ float bf2f(ushort u) {
    union { uint32_t i; float f; } v; v.i = ((uint32_t)u) << 16; return v.f;
}

// async global->LDS, 16 bytes per lane; LDS dest must be wave-uniform base
__device__ __forceinline__ void glds16(const ushort* g, ushort* l) {
    __builtin_amdgcn_global_load_lds(
        (__attribute__((address_space(1))) void*)(void*)const_cast<ushort*>(g),
        (__attribute__((address_space(3))) void*)l, 16, 0, 0);
}

// f32 [K][N] 32x32 tile -> bf16 [N][K]
__device__ __forceinline__ void tr_tile(
    const float* __restrict__ in, ushort* __restrict__ out,
    int K, int N, int bx, int by, float (*t)[33], int tid)
{
    int n0 = bx * 32, k0 = by * 32;
    int tx = tid & 31, ty = tid >> 5;
    #pragma unroll
    for (int dy = 0; dy < 32; dy += 8)
        t[ty + dy][tx] = in[(size_t)(k0 + ty + dy) * N + n0 + tx];
    __syncthreads();
    #pragma unroll
    for (int dy = 0; dy < 32; dy += 8)
        out[(size_t)(n0 + ty + dy) * K + k0 + tx] = f2bf(t[tx][ty + dy]);
}

// ---------------------------------------------------------------------------
// bf16 MFMA GEMM: C[M,N] = A[M,K] @ Bt[N,K]^T + bias.
// 128x128 tile, BK=32, double-buffered LDS (32KB -> ~4-5 blocks/CU),
// prefetch(t+1) issued before compute(t), ONE __syncthreads per K-tile.
// Blocks [0, nblk): GEMM (XCD-swizzled within nblk; nblk % 8 == 0).
// FILL: blocks [nblk, ...) write 1/L into score rows with rowsel==0.
// AUX:  blocks [nblk, ...) do Wo/W1/W2 transposes + rowsel zeroing (ride
//       along with the QKV GEMM; outputs consumed >=2 launches later).
// MODE: 0 = f32 out; 1 = bf16 out; 2 = relu + bf16 out
// ---------------------------------------------------------------------------
template<int MODE, int FILL, int AUX>
__global__ __launch_bounds__(256) void gemm_mfma(
    const ushort* __restrict__ A, const ushort* __restrict__ Bt,
    const float* __restrict__ bias, void* __restrict__ out0,
    int M, int N, int K, int nxb, int nblk,
    float* __restrict__ fillbuf, const int* __restrict__ rowsel, int fill_base,
    const float* __restrict__ Wof, const float* __restrict__ W1f,
    const float* __restrict__ W2f, ushort* __restrict__ Wot,
    ushort* __restrict__ W1t, ushort* __restrict__ W2t,
    int* __restrict__ rowz)
{
    __shared__ ushort As[2][128 * 32];
    __shared__ ushort Bs[2][128 * 32];
    const int tid = threadIdx.x;

    if (FILL && (int)blockIdx.x >= nblk) {
        int fb = (blockIdx.x - nblk) + fill_base;    // group of 4 score rows
        const float iv = 1.0f / (float)Lc;
        f32x4 v4 = {iv, iv, iv, iv};
        #pragma unroll
        for (int r = 0; r < 4; ++r) {
            int row = fb * 4 + r;
            if (rowsel[row] == 0)
                __builtin_nontemporal_store(
                    v4, reinterpret_cast<f32x4*>(fillbuf + (size_t)row * Lc) + tid);
        }
        return;
    }

    if (AUX && (int)blockIdx.x >= nblk) {
        float (*t)[33] = reinterpret_cast<float(*)[33]>(&As[0][0]);  // alias GEMM LDS
        int bid = blockIdx.x - nblk;
        if (bid < 256) { tr_tile(Wof, Wot, 512, 512, bid & 15, bid >> 4, t, tid); return; }
        bid -= 256;
        if (bid < 1024) { tr_tile(W1f, W1t, 512, 2048, bid & 63, bid >> 6, t, tid); return; }
        bid -= 1024;
        if (bid < 1024) { tr_tile(W2f, W2t, 2048, 512, bid & 15, bid >> 4, t, tid); return; }
        bid -= 1024;
        // zero rowsel: 131072 ints = 32768 uint4 over 128 blocks
        reinterpret_cast<uint4*>(rowz)[bid * 256 + tid] = make_uint4(0, 0, 0, 0);
        return;
    }

    int wg = blockIdx.x;
    wg = (wg & 7) * (nblk >> 3) + (wg >> 3);     // XCD swizzle (nblk%8==0)
    const int n0 = (wg % nxb) * 128;
    const int m0 = (wg / nxb) * 128;

    const int lane = tid & 63;
    const int wave = tid >> 6;
    const int wr = wave >> 1, wc = wave & 1;
    const int lrow = lane & 15;
    const int lk = (lane >> 4) * 8;

    f32x4 zero = {0.f, 0.f, 0.f, 0.f};
    f32x4 acc[4][4];
    #pragma unroll
    for (int m = 0; m < 4; ++m)
        #pragma unroll
        for (int n = 0; n < 4; ++n) acc[m][n] = zero;

    const int srow = tid >> 2;            // 0..63
    const int skc = (tid & 3) * 8;        // 0,8,16,24
    const int ldsb = (tid & 192) * 8;     // wave * 512 elements

    auto stage = [&](int k0, int bufi) {
        glds16(A  + (size_t)(m0 + srow) * K + k0 + skc,      &As[bufi][ldsb]);
        glds16(A  + (size_t)(m0 + 64 + srow) * K + k0 + skc, &As[bufi][2048 + ldsb]);
        glds16(Bt + (size_t)(n0 + srow) * K + k0 + skc,      &Bs[bufi][ldsb]);
        glds16(Bt + (size_t)(n0 + 64 + srow) * K + k0 + skc, &Bs[bufi][2048 + ldsb]);
    };

    const int nt = K >> 5;
    stage(0, 0);
    __syncthreads();
    int cur = 0;
    for (int t = 0; t < nt; ++t) {
        if (t + 1 < nt) stage((t + 1) << 5, cur ^ 1);   // prefetch next tile
        bf16x8 af[4], bv[4];
        #pragma unroll
        for (int m = 0; m < 4; ++m)
            af[m] = *reinterpret_cast<const bf16x8*>(&As[cur][(wr * 64 + m * 16 + lrow) * 32 + lk]);
        #pragma unroll
        for (int n = 0; n < 4; ++n)
            bv[n] = *reinterpret_cast<const bf16x8*>(&Bs[cur][(wc * 64 + n * 16 + lrow) * 32 + lk]);
        #pragma unroll
        for (int m = 0; m < 4; ++m)
            #pragma unroll
            for (int n = 0; n < 4; ++n)
                acc[m][n] = __builtin_amdgcn_mfma_f32_16x16x32_bf16(af[m], bv[n], acc[m][n], 0, 0, 0);
        __syncthreads();   // vmcnt(0) drain: prefetch landed; republish LDS
        cur ^= 1;
    }

    #pragma unroll
    for (int n = 0; n < 4; ++n) {
        int col = n0 + wc * 64 + n * 16 + lrow;
        float bval = bias[col];
        #pragma unroll
        for (int m = 0; m < 4; ++m) {
            #pragma unroll
            for (int j = 0; j < 4; ++j) {
                int row = m0 + wr * 64 + m * 16 + (lane >> 4) * 4 + j;
                float v = acc[m][n][j] + bval;
                if (MODE == 2) v = fmaxf(v, 0.0f);
                if (MODE == 0)
                    ((float*)out0)[(size_t)row * N + col] = v;
                else
                    ((ushort*)out0)[(size_t)row * N + col] = f2bf(v);
            }
        }
    }
}

// ---------------------------------------------------------------------------
// Prep (critical path for QKV only): x->bf16, Wq/Wk/Wv transposes, bias cat.
// ---------------------------------------------------------------------------
__global__ __launch_bounds__(256) void prep_kernel(
    const float* __restrict__ x,
    const float* __restrict__ Wq, const float* __restrict__ Wk,
    const float* __restrict__ Wv,
    const float* __restrict__ bq, const float* __restrict__ bk,
    const float* __restrict__ bv,
    ushort* __restrict__ xbf, ushort* __restrict__ Wqkvt,
    float* __restrict__ bcat)
{
    __shared__ float t[32][33];
    const int tid = threadIdx.x;
    int bid = blockIdx.x;
    if (bid < 8192) {   // x -> bf16 (float4 per thread)
        int i = bid * 256 + tid;
        float4 v = reinterpret_cast<const float4*>(x)[i];
        uint32_t lo = (uint32_t)f2bf(v.x) | ((uint32_t)f2bf(v.y) << 16);
        uint32_t hi = (uint32_t)f2bf(v.z) | ((uint32_t)f2bf(v.w) << 16);
        reinterpret_cast<uint2*>(xbf)[i] = make_uint2(lo, hi);
        return;
    }
    bid -= 8192;
    if (bid < 256) { tr_tile(Wq, Wqkvt,              512, 512, bid & 15, bid >> 4, t, tid); return; }
    bid -= 256;
    if (bid < 256) { tr_tile(Wk, Wqkvt + 512 * 512,  512, 512, bid & 15, bid >> 4, t, tid); return; }
    bid -= 256;
    if (bid < 256) { tr_tile(Wv, Wqkvt + 1024 * 512, 512, 512, bid & 15, bid >> 4, t, tid); return; }
    // bias concat (one block)
    for (int i = tid; i < 1536; i += 256)
        bcat[i] = (i < 512) ? bq[i] : (i < 1024) ? bk[i - 512] : bv[i - 1024];
}

// ---------------------------------------------------------------------------
// compute_M: lane = sample. Wave per (b,h,l).
// QKV layout: [b*L+l][Q(512) | K(512) | V(512)] bf16, row stride 1536.
// ---------------------------------------------------------------------------
__global__ __launch_bounds__(256) void compute_M_kernel(
    const ushort* __restrict__ QKV, const int* __restrict__ idx,
    float* __restrict__ Mout)
{
    __shared__ float qs[4][64];
    const int tid = threadIdx.x;
    const int wid = tid >> 6;
    const int lane = tid & 63;
    const int task = blockIdx.x * 4 + wid;     // (b,h,l)
    const int l = task & (Lc - 1);
    const int bh = task >> 10;
    const int h = bh & (Hc - 1);
    const int b = bh >> 3;

    qs[wid][lane] = bf2f(QKV[(size_t)(b * Lc + l) * 1536 + h * 64 + lane]);

    const bool act = lane < Uc;
    int kl = act ? idx[l * Uc + lane] : 0;
    const bf16x8* kr = reinterpret_cast<const bf16x8*>(
        QKV + (size_t)(b * Lc + kl) * 1536 + 512 + h * 64);
    float dot = 0.0f;
    if (act) {
        #pragma unroll
        for (int c = 0; c < 8; ++c) {
            bf16x8 kv = kr[c];
            #pragma unroll
            for (int e = 0; e < 8; ++e)
                dot += qs[wid][c * 8 + e] * bf2f((ushort)kv[e]);
        }
    }
    float mx = act ? dot : -INFINITY;
    float sm = act ? dot : 0.0f;
    #pragma unroll
    for (int off = 32; off; off >>= 1) {
        mx = fmaxf(mx, __shfl_xor(mx, off, 64));
        sm += __shfl_xor(sm, off, 64);
    }
    if (lane == 0) Mout[task] = mx - sm * (1.0f / Uc);
}

// ---------------------------------------------------------------------------
// Top-u per (b,h): register-resident values, wave shfl reduce.
// Tie-break lowest index. Also sets rowsel[bh*1024 + idx] = 1.
// ---------------------------------------------------------------------------
__global__ __launch_bounds__(256) void topk_kernel(
    const float* __restrict__ Mvals, int* __restrict__ Mtop,
    int* __restrict__ rowsel)
{
    const int bh = blockIdx.x;
    const int t = threadIdx.x;
    const int lane = t & 63, wid = t >> 6;
    float v[4];
    #pragma unroll
    for (int c = 0; c < 4; ++c) v[c] = Mvals[((size_t)bh << 10) + t + 256 * c];

    __shared__ float cv[4];
    __shared__ int   ci[4];
    __shared__ int   wini;

    for (int j = 0; j < Uc; ++j) {
        float bv = v[0]; int bi = t;
        #pragma unroll
        for (int c = 1; c < 4; ++c)
            if (v[c] > bv) { bv = v[c]; bi = t + 256 * c; }   // strict > keeps lower idx
        #pragma unroll
        for (int off = 32; off; off >>= 1) {
            float ov = __shfl_xor(bv, off, 64);
            int   oi = __shfl_xor(bi, off, 64);
            if (ov > bv || (ov == bv && oi < bi)) { bv = ov; bi = oi; }
        }
        if (lane == 0) { cv[wid] = bv; ci[wid] = bi; }
        __syncthreads();
        if (t == 0) {
            float fv = cv[0]; int fi = ci[0];
            #pragma unroll
            for (int w = 1; w < 4; ++w)
                if (cv[w] > fv || (cv[w] == fv && ci[w] < fi)) { fv = cv[w]; fi = ci[w]; }
            Mtop[bh * Uc + j] = fi;
            rowsel[(bh << 10) + fi] = 1;
            wini = fi;
        }
        __syncthreads();
        int wi = wini;
        if ((wi & 255) == t) v[wi >> 8] = -INFINITY;
    }
}

// ---------------------------------------------------------------------------
// QK scores: block per (b,h, l-chunk of 256). Thread owns one K row (bf16,
// read once); Q_reduce rows broadcast from LDS. Writes RAW S into the
// selected rows of score_out.
// ---------------------------------------------------------------------------
__global__ __launch_bounds__(256) void qk_scores_kernel(
    const ushort* __restrict__ QKV, const int* __restrict__ Mtop,
    float* __restrict__ score)
{
    const int bh = blockIdx.x >> 2;
    const int l0 = (blockIdx.x & 3) * 256;
    const int h = bh & (Hc - 1), b = bh >> 3;
    __shared__ int qpos[Uc];
    __shared__ float Qs[Uc][64];
    const int t = threadIdx.x;
    if (t < Uc) qpos[t] = Mtop[bh * Uc + t];
    __syncthreads();
    for (int i = t; i < Uc * 64; i += 256) {
        int j = i >> 6, d = i & 63;
        Qs[j][d] = bf2f(QKV[(size_t)(b * Lc + qpos[j]) * 1536 + h * 64 + d]);
    }
    __syncthreads();

    const int l = l0 + t;
    const bf16x8* kr = reinterpret_cast<const bf16x8*>(
        QKV + (size_t)(b * Lc + l) * 1536 + 512 + h * 64);
    float acc[Uc] = {};
    #pragma unroll
    for (int c = 0; c < 8; ++c) {
        bf16x8 kv = kr[c];
        float kf[8];
        #pragma unroll
        for (int e = 0; e < 8; ++e) kf[e] = bf2f((ushort)kv[e]);
        #pragma unroll
        for (int j = 0; j < Uc; ++j) {
            float s = 0.0f;
            #pragma unroll
            for (int e = 0; e < 8; ++e) s += Qs[j][c * 8 + e] * kf[e];
            acc[j] += s;
        }
    }
    #pragma unroll
    for (int j = 0; j < Uc; ++j)
        score[((size_t)(bh << 10) + qpos[j]) * Lc + l] = acc[j] * 0.125f;
}

// ---------------------------------------------------------------------------
// Fused attention output: block per (b,h), 256 threads (64 d x 4 part).
// Phase A: softmax stats of 35 raw rows (in score_out).
// Phase B: probs -> LDS + score_out; single V sweep (bf16) for PV + V-mean.
// Phase C: ctx = mean rows everywhere, PV on selected rows.
// ---------------------------------------------------------------------------
__global__ __launch_bounds__(256) void attn_out_kernel(
    float* __restrict__ score, const ushort* __restrict__ QKV,
    const int* __restrict__ Mtop, ushort* __restrict__ ctx)
{
    const int bh = blockIdx.x;
    const int h = bh & (Hc - 1), b = bh >> 3;
    const int t = threadIdx.x;
    const int d = t & 63, part = t >> 6;

    __shared__ int qpos[Uc];
    __shared__ float mz[Uc][2];
    __shared__ float buf[4][Uc][64];   // prob chunk staging, then PV partials
    __shared__ float vmred[4][64];
    __shared__ float vmf[64];

    if (t < Uc) qpos[t] = Mtop[bh * Uc + t];
    __syncthreads();

    // Phase A: m_j, 1/Z_j (raw rows untouched)
    for (int j = part; j < Uc; j += 4) {
        const float* row = score + ((size_t)(bh << 10) + qpos[j]) * Lc;
        float v[16];
        float mx = -INFINITY;
        #pragma unroll
        for (int c = 0; c < 16; ++c) { v[c] = row[c * 64 + d]; mx = fmaxf(mx, v[c]); }
        #pragma unroll
        for (int off = 32; off; off >>= 1) mx = fmaxf(mx, __shfl_xor(mx, off, 64));
        float z = 0.0f;
        #pragma unroll
        for (int c = 0; c < 16; ++c) z += expf(v[c] - mx);
        #pragma unroll
        for (int off = 32; off; off >>= 1) z += __shfl_xor(z, off, 64);
        if (d == 0) { mz[j][0] = mx; mz[j][1] = 1.0f / z; }
    }
    __syncthreads();

    // Phase B: V sweep (bf16) with on-the-fly probs
    float acc[Uc];
    #pragma unroll
    for (int j = 0; j < Uc; ++j) acc[j] = 0.0f;
    float vm = 0.0f;

    for (int c = 0; c < 4; ++c) {
        const int l0 = part * 256 + c * 64;
        #pragma unroll
        for (int j = 0; j < Uc; ++j) {
            size_t off = ((size_t)(bh << 10) + qpos[j]) * Lc + l0 + d;
            float p = expf(score[off] - mz[j][0]) * mz[j][1];
            buf[part][j][d] = p;
            score[off] = p;                 // final prob (never re-read here)
        }
        __syncthreads();
        #pragma unroll 4
        for (int li = 0; li < 64; ++li) {
            float v = bf2f(QKV[((size_t)(b << 10) + l0 + li) * 1536 + 1024 + h * 64 + d]);
            vm += v;
            #pragma unroll
            for (int j = 0; j < Uc; ++j) acc[j] += buf[part][j][li] * v;
        }
        __syncthreads();
    }

    // PV partials + mean partials into LDS
    #pragma unroll
    for (int j = 0; j < Uc; ++j) buf[part][j][d] = acc[j];
    vmred[part][d] = vm;
    __syncthreads();
    if (t < 64) vmf[t] = (vmred[0][t] + vmred[1][t] + vmred[2][t] + vmred[3][t]) * (1.0f / Lc);
    __syncthreads();

    // Phase C1: default (mean) rows for ALL l
    const int dcol = (t & 15) * 4;
    ushort4 vmu;
    vmu.x = f2bf(vmf[dcol + 0]); vmu.y = f2bf(vmf[dcol + 1]);
    vmu.z = f2bf(vmf[dcol + 2]); vmu.w = f2bf(vmf[dcol + 3]);
    for (int li = 0; li < 64; ++li) {
        int l = (t >> 4) + li * 16;
        *reinterpret_cast<ushort4*>(ctx + ((size_t)(b << 10) + l) * 512 + h * 64 + dcol) = vmu;
    }
    __syncthreads();   // drain default writes before overwriting selected rows

    // Phase C2: selected rows = PV
    for (int idx = t; idx < Uc * 64; idx += 256) {
        int j = idx >> 6, d2 = idx & 63;
        float s = buf[0][j][d2] + buf[1][j][d2] + buf[2][j][d2] + buf[3][j][d2];
        ctx[((size_t)(b << 10) + qpos[j]) * 512 + h * 64 + d2] = f2bf(s);
    }
}

// ---------------------------------------------------------------------------
// LayerNorm(a + b) * g + beta over DM=512. Thread handles elems 2t, 2t+1.
// ---------------------------------------------------------------------------
template<int A_BF, int B_BF, int OUT_BF>
__global__ __launch_bounds__(256) void ln_kernel(
    const void* __restrict__ a, const void* __restrict__ bsrc,
    const float* __restrict__ g, const float* __restrict__ beta,
    void* __restrict__ y)
{
    const int row = blockIdx.x;
    const int t = threadIdx.x;
    float a0, a1, b0, b1;
    if (A_BF) {
        uint32_t u = ((const uint32_t*)a)[(size_t)row * 256 + t];
        a0 = bf2f((ushort)(u & 0xffff)); a1 = bf2f((ushort)(u >> 16));
    } else {
        float2 f = ((const float2*)a)[(size_t)row * 256 + t];
        a0 = f.x; a1 = f.y;
    }
    if (B_BF) {
        uint32_t u = ((const uint32_t*)bsrc)[(size_t)row * 256 + t];
        b0 = bf2f((ushort)(u & 0xffff)); b1 = bf2f((ushort)(u >> 16));
    } else {
        float2 f = ((const float2*)bsrc)[(size_t)row * 256 + t];
        b0 = f.x; b1 = f.y;
    }
    float v0 = a0 + b0, v1 = a1 + b1;
    __shared__ float red[256];
    red[t] = v0 + v1; __syncthreads();
    for (int s = 128; s; s >>= 1) { if (t < s) red[t] += red[t + s]; __syncthreads(); }
    float mean = red[0] * (1.0f / DMc);
    __syncthreads();
    float d0 = v0 - mean, d1 = v1 - mean;
    red[t] = d0 * d0 + d1 * d1; __syncthreads();
    for (int s = 128; s; s >>= 1) { if (t < s) red[t] += red[t + s]; __syncthreads(); }
    float inv = rsqrtf(red[0] * (1.0f / DMc) + 1e-5f);
    float2 gv = ((const float2*)g)[t];
    float2 bt = ((const float2*)beta)[t];
    float o0 = gv.x * d0 * inv + bt.x;
    float o1 = gv.y * d1 * inv + bt.y;
    if (OUT_BF) {
        uint32_t u = (uint32_t)f2bf(o0) | ((uint32_t)f2bf(o1) << 16);
        ((uint32_t*)y)[(size_t)row * 256 + t] = u;
    } else {
        ((float2*)y)[(size_t)row * 256 + t] = make_float2(o0, o1);
    }
}

// ---------------------------------------------------------------------------
extern "C" void kernel_launch(void* const* d_in, const int* in_sizes, int n_in,
                              void* d_out, int out_size, void* d_ws, size_t ws_size,
                              hipStream_t stream)
{
    const float* x     = (const float*)d_in[0];
    const float* Wq    = (const float*)d_in[1];
    const float* bq    = (const float*)d_in[2];
    const float* Wk    = (const float*)d_in[3];
    const float* bk    = (const float*)d_in[4];
    const float* Wv    = (const float*)d_in[5];
    const float* bv    = (const float*)d_in[6];
    const float* Wo    = (const float*)d_in[7];
    const float* bo    = (const float*)d_in[8];
    const float* g1    = (const float*)d_in[9];
    const float* beta1 = (const float*)d_in[10];
    const float* W1    = (const float*)d_in[11];
    const float* bf1   = (const float*)d_in[12];
    const float* W2    = (const float*)d_in[13];
    const float* bf2   = (const float*)d_in[14];
    const float* g2    = (const float*)d_in[15];
    const float* beta2 = (const float*)d_in[16];
    const int* index_sample = (const int*)d_in[17];

    const size_t NTOK = (size_t)Bc * Lc;            // 16384
    const size_t QKV_SZ = NTOK * DMc;               // 8,388,608
    const size_t HID_SZ = NTOK * DHc;

    char* p = (char*)d_ws;
    auto alloc = [&](size_t bytes) { char* r = p; p += (bytes + 255) & ~(size_t)255; return r; };
    ushort* QKVbf  = (ushort*)alloc(NTOK * 1536 * 2);   // [tok][Q|K|V] bf16
    ushort* hidden = (ushort*)alloc(HID_SZ * 2);
    ushort* xbf    = (ushort*)alloc(QKV_SZ * 2);
    ushort* ctxbf  = (ushort*)alloc(QKV_SZ * 2);
    ushort* x1bf   = (ushort*)alloc(QKV_SZ * 2);
    ushort* projbf = (ushort*)alloc(QKV_SZ * 2);
    ushort* ffnbf  = (ushort*)alloc(QKV_SZ * 2);
    ushort* Wqkvt  = (ushort*)alloc((size_t)1536 * 512 * 2);
    ushort* Wot    = (ushort*)alloc((size_t)512 * 512 * 2);
    ushort* W1t    = (ushort*)alloc((size_t)512 * 2048 * 2);
    ushort* W2t    = (ushort*)alloc((size_t)512 * 2048 * 2);
    float*  bcat   = (float*) alloc(1536 * 4);
    float*  Mbuf   = (float*) alloc((size_t)Bc * Hc * Lc * 4);
    int*    Mtop   = (int*)   alloc((size_t)Bc * Hc * 64 * 4);
    int*    rowsel = (int*)   alloc((size_t)Bc * Hc * Lc * 4);   // 512KB flags

    float* x2_out    = (float*)d_out;
    float* score_out = x2_out + QKV_SZ;

    dim3 blk(256);

    // prep (QKV critical path only): x->bf16, Wq/Wk/Wv transposes, bias cat
    prep_kernel<<<PREP_BLKS, blk, 0, stream>>>(
        x, Wq, Wk, Wv, bq, bk, bv, xbf, Wqkvt, bcat);

    // fused QKV projection -> [tok][Q|K|V] bf16; AUX blocks ride along doing
    // Wo/W1/W2 transposes + rowsel zeroing (outputs used >=2 launches later)
    gemm_mfma<1, 0, 1><<<12 * 128 + AUX_BLKS, blk, 0, stream>>>(
        xbf, Wqkvt, bcat, QKVbf, (int)NTOK, 1536, 512, 12, 12 * 128,
        nullptr, nullptr, 0, Wo, W1, W2, Wot, W1t, W2t, rowsel);

    // ProbSparse selection (topk also sets rowsel flags)
    compute_M_kernel<<<(Bc * Hc * Lc) / 4, blk, 0, stream>>>(QKVbf, index_sample, Mbuf);
    topk_kernel<<<Bc * Hc, blk, 0, stream>>>(Mbuf, Mtop, rowsel);

    // raw scores into selected score rows, then softmax+PV+ctx
    qk_scores_kernel<<<Bc * Hc * 4, blk, 0, stream>>>(QKVbf, Mtop, score_out);
    attn_out_kernel<<<Bc * Hc, blk, 0, stream>>>(score_out, QKVbf, Mtop, ctxbf);

    // output projection (bf16) + LN1 -> x1 (bf16); residual from xbf
    gemm_mfma<1, 0, 0><<<4 * 128, blk, 0, stream>>>(
        ctxbf, Wot, bo, projbf, (int)NTOK, 512, 512, 4, 4 * 128,
        nullptr, nullptr, 0, nullptr, nullptr, nullptr, nullptr, nullptr, nullptr, nullptr);
    ln_kernel<1, 1, 1><<<(int)NTOK, blk, 0, stream>>>(projbf, xbf, g1, beta1, x1bf);

    // FFN1 + first half of score default fill (hidden under MFMA)
    gemm_mfma<2, 1, 0><<<16 * 128 + FILL_BLKS, blk, 0, stream>>>(
        x1bf, W1t, bf1, hidden, (int)NTOK, 2048, 512, 16, 16 * 128,
        score_out, rowsel, 0, nullptr, nullptr, nullptr, nullptr, nullptr, nullptr, nullptr);
    // FFN2 + second half of fill
    gemm_mfma<1, 1, 0><<<4 * 128 + FILL_BLKS, blk, 0, stream>>>(
        hidden, W2t, bf2, ffnbf, (int)NTOK, 512, 2048, 4, 4 * 128,
        score_out, rowsel, FILL_BLKS, nullptr, nullptr, nullptr, nullptr, nullptr, nullptr, nullptr);
    ln_kernel<1, 1, 0><<<(int)NTOK, blk, 0, stream>>>(ffnbf, x1bf, g2, beta2, x2_out);
}